// Round 2
// baseline (510.627 us; speedup 1.0000x reference)
//
#include <hip/hip_runtime.h>
#include <hip/hip_bf16.h>
#include <math.h>

#define N_ATOMS 512
#define NF 64
#define NB 8
#define NBINS 64

// out = x  (d_out is poisoned before every timed launch)
__global__ void init_out_kernel(const float* __restrict__ x, float* __restrict__ out, int n) {
    int idx = blockIdx.x * blockDim.x + threadIdx.x;
    if (idx < n) out[idx] = x[idx];
}

__device__ __forceinline__ float dot3(float ax, float ay, float az,
                                      float bx, float by, float bz) {
    return fmaf(ax, bx, fmaf(ay, by, az * bz));
}

// lane = edge layout: each lane owns one (b, e) edge-batch; rbf/h/m vectors in registers.
__launch_bounds__(256, 2)
__global__ void writhe_msg_kernel(
        const float* __restrict__ x, const float* __restrict__ xyz,
        const int* __restrict__ seg,
        const float* __restrict__ W1, const float* __restrict__ b1,
        const float* __restrict__ W2, const float* __restrict__ b2,
        float* __restrict__ out, int P, int n_tiles) {
    // bf16 m-staging: 4 waves * 64 edges * 65(pad) * 2B = 33 KB
    __shared__ __hip_bfloat16 lds_m[4][64 * 65];
    __shared__ int lds_i[4][64];
    __shared__ int lds_j[4][64];

    const int widx = threadIdx.x >> 6;
    const int lane = threadIdx.x & 63;
    const int wave_g = blockIdx.x * 4 + widx;
    const int b = wave_g / n_tiles;
    const int tile = wave_g - b * n_tiles;
    const int bc = (b < NB) ? b : 0;           // defensive clamp for tail waves
    const int e = tile * 64 + lane;
    const bool valid = (b < NB) && (e < P);

    // ---- edge endpoints (segments rows are [i, i+1, j, j+1]) ----
    int4 sv = valid ? ((const int4*)seg)[e] : make_int4(0, 1, 2, 3);
    const int i = sv.x;
    const int j = sv.z;

    // ---- writhe (per-lane scalar geometry) ----
    const float* pb = xyz + bc * (N_ATOMS * 3);
    float p0x = pb[3*i+0], p0y = pb[3*i+1], p0z = pb[3*i+2];
    float p1x = pb[3*i+3], p1y = pb[3*i+4], p1z = pb[3*i+5];
    float p2x = pb[3*j+0], p2y = pb[3*j+1], p2z = pb[3*j+2];
    float p3x = pb[3*j+3], p3y = pb[3*j+4], p3z = pb[3*j+5];

    // disp: d0=n(p2-p0) d1=n(p3-p0) d2=n(p2-p1) d3=n(p3-p1)
    float d0x = p2x-p0x, d0y = p2y-p0y, d0z = p2z-p0z;
    float d1x = p3x-p0x, d1y = p3y-p0y, d1z = p3z-p0z;
    float d2x = p2x-p1x, d2y = p2y-p1y, d2z = p2z-p1z;
    float d3x = p3x-p1x, d3y = p3y-p1y, d3z = p3z-p1z;
    {
        float n0 = rsqrtf(dot3(d0x,d0y,d0z,d0x,d0y,d0z)); d0x*=n0; d0y*=n0; d0z*=n0;
        float n1 = rsqrtf(dot3(d1x,d1y,d1z,d1x,d1y,d1z)); d1x*=n1; d1y*=n1; d1z*=n1;
        float n2 = rsqrtf(dot3(d2x,d2y,d2z,d2x,d2y,d2z)); d2x*=n2; d2y*=n2; d2z*=n2;
        float n3 = rsqrtf(dot3(d3x,d3y,d3z,d3x,d3y,d3z)); d3x*=n3; d3y*=n3; d3z*=n3;
    }
    // crosses (per reference idx_a=[0,1,3,2], idx_b=[1,3,2,0]):
    //   c0=n(d0xd1) c1=n(d1xd3) c2=n(d3xd2) c3=n(d2xd0)
    // dots pair crosses[k] with crosses[idx_b[k]]:
    //   (c0.c1), (c1.c3), (c2.c2)==1 -> asin = pi/2, (c3.c0)
    float c0x = d0y*d1z - d0z*d1y, c0y = d0z*d1x - d0x*d1z, c0z = d0x*d1y - d0y*d1x;
    float c1x = d1y*d3z - d1z*d3y, c1y = d1z*d3x - d1x*d3z, c1z = d1x*d3y - d1y*d3x;
    float c3x = d2y*d0z - d2z*d0y, c3y = d2z*d0x - d2x*d0z, c3z = d2x*d0y - d2y*d0x;
    {
        float n0 = rsqrtf(dot3(c0x,c0y,c0z,c0x,c0y,c0z)); c0x*=n0; c0y*=n0; c0z*=n0;
        float n1 = rsqrtf(dot3(c1x,c1y,c1z,c1x,c1y,c1z)); c1x*=n1; c1y*=n1; c1z*=n1;
        float n3 = rsqrtf(dot3(c3x,c3y,c3z,c3x,c3y,c3z)); c3x*=n3; c3y*=n3; c3z*=n3;
    }
    float t0 = fminf(fmaxf(dot3(c0x,c0y,c0z, c1x,c1y,c1z), -1.f), 1.f);
    float t1 = fminf(fmaxf(dot3(c1x,c1y,c1z, c3x,c3y,c3z), -1.f), 1.f);
    float t3 = fminf(fmaxf(dot3(c3x,c3y,c3z, c0x,c0y,c0z), -1.f), 1.f);
    float omega = asinf(t0) + asinf(t1) + asinf(t3) + 1.5707963267948966f;
    // sign((p3-p2)x(p1-p0) . d0) — positive normalization factors dropped
    float ex = p3x-p2x, ey = p3y-p2y, ez = p3z-p2z;
    float fx = p1x-p0x, fy = p1y-p0y, fz = p1z-p0z;
    float gx = ey*fz - ez*fy, gy = ez*fx - ex*fz, gz = ex*fy - ey*fx;
    float sgd = dot3(gx,gy,gz, d0x,d0y,d0z);
    float sgn = (sgd > 0.f) ? 1.f : ((sgd < 0.f) ? -1.f : 0.f);
    float wr = omega * sgn * 0.15915494309189535f;  // /(2*pi)

    // ---- RBF: bins at v_k = -1 + 2k/63, step = 2/63 -> d = (wr+1)*31.5 - k ----
    float acc_[NBINS];   // holds rbf, later reused for m
    {
        float tt = (wr + 1.0f) * 31.5f;
        #pragma unroll
        for (int k = 0; k < NBINS; ++k) {
            float d = tt - (float)k;
            acc_[k] = __expf(-d * d) * 0.8928571428571429f;  // /1.12
        }
    }

    // ---- GEMM1: h = leaky_relu(rbf @ W1 + b1) ----
    float h_[NF];
    #pragma unroll
    for (int f = 0; f < NF; ++f) h_[f] = b1[f];
    #pragma unroll
    for (int k = 0; k < NBINS; ++k) {
        float r = acc_[k];
        #pragma unroll
        for (int f = 0; f < NF; ++f) h_[f] = fmaf(r, W1[k * NF + f], h_[f]);
    }
    #pragma unroll
    for (int f = 0; f < NF; ++f) h_[f] = fmaxf(h_[f], 0.01f * h_[f]);

    // ---- GEMM2: m = h @ W2 + b2 (into acc_) ----
    #pragma unroll
    for (int f = 0; f < NF; ++f) acc_[f] = b2[f];
    #pragma unroll
    for (int k = 0; k < NF; ++k) {
        float hk = h_[k];
        #pragma unroll
        for (int f = 0; f < NF; ++f) acc_[f] = fmaf(hk, W2[k * NF + f], acc_[f]);
    }

    // ---- transpose m through LDS (lane=edge -> lane=feature) ----
    const float scale = valid ? 1.0f : 0.0f;   // invalid lanes contribute exactly 0
    #pragma unroll
    for (int f = 0; f < NF; ++f)
        lds_m[widx][lane * 65 + f] = __float2bfloat16(acc_[f] * scale);
    lds_i[widx][lane] = i;
    lds_j[widx][lane] = j;
    __syncthreads();

    // ---- epilogue: lane = feature; coalesced x-gather + atomics ----
    const float* xb = x + bc * (N_ATOMS * NF);
    float* ob = out + bc * (N_ATOMS * NF);
    int cur_i = lds_i[widx][0];
    float acc_i = 0.0f;   // register pre-accumulation for the (mostly constant) i side
    for (int ee = 0; ee < 64; ++ee) {
        int ie = lds_i[widx][ee];
        int je = lds_j[widx][ee];
        float mv = __bfloat162float(lds_m[widx][ee * 65 + lane]);
        float xi = xb[ie * NF + lane];
        float xj = xb[je * NF + lane];
        atomicAdd(&ob[je * NF + lane], mv * xi);   // msg i->j (j varies every iter: no contention)
        if (ie != cur_i) {
            atomicAdd(&ob[cur_i * NF + lane], acc_i);
            acc_i = 0.0f;
            cur_i = ie;
        }
        acc_i = fmaf(mv, xj, acc_i);               // msg j->i accumulated while i constant
    }
    atomicAdd(&ob[cur_i * NF + lane], acc_i);
}

extern "C" void kernel_launch(void* const* d_in, const int* in_sizes, int n_in,
                              void* d_out, int out_size, void* d_ws, size_t ws_size,
                              hipStream_t stream) {
    const float* x   = (const float*)d_in[0];
    const float* xyz = (const float*)d_in[1];
    const int*   seg = (const int*)d_in[2];
    const float* W1  = (const float*)d_in[3];
    const float* b1  = (const float*)d_in[4];
    const float* W2  = (const float*)d_in[5];
    const float* b2  = (const float*)d_in[6];
    float* out = (float*)d_out;

    const int P = in_sizes[2] / 4;            // 129795 edges
    const int n_tiles = (P + 63) / 64;        // 64 edges per wave
    const int n = out_size;                   // 8*512*64

    hipLaunchKernelGGL(init_out_kernel, dim3((n + 255) / 256), dim3(256), 0, stream,
                       x, out, n);

    const int total_waves = NB * n_tiles;
    const int blocks = (total_waves + 3) / 4; // 4 waves per block
    hipLaunchKernelGGL(writhe_msg_kernel, dim3(blocks), dim3(256), 0, stream,
                       x, xyz, seg, W1, b1, W2, b2, out, P, n_tiles);
}